// Round 1
// baseline (252.279 us; speedup 1.0000x reference)
//
#include <hip/hip_runtime.h>
#include <hip/hip_fp16.h>

typedef _Float16 half8 __attribute__((ext_vector_type(8)));
typedef float floatx4 __attribute__((ext_vector_type(4)));

__device__ __forceinline__ void async_ld16(const void* g, void* l) {
    __builtin_amdgcn_global_load_lds(
        (const __attribute__((address_space(1))) char*)g,
        (__attribute__((address_space(3))) char*)l, 16, 0, 0);
}

__device__ __forceinline__ float elu_f(float v) {
    return v > 0.f ? v : expm1f(v);
}

// ---------------------------------------------------------------------------
// prep: convert all fp32 inputs to fp16 working buffers.
//  X0  [4096][320] = [x | z]
//  h0/h1/h2 [4096][544]: cols 512..543 = z (cols 0..511 written by GEMMs)
//  Wc* = flat fp16 copies of expert weights, gW*c = gating weights
// ---------------------------------------------------------------------------
__global__ void prep_kernel(const float* __restrict__ x, const float* __restrict__ z,
                            const float* __restrict__ W0, const float* __restrict__ W1,
                            const float* __restrict__ W2, const float* __restrict__ W3,
                            const float* __restrict__ gW1, const float* __restrict__ gW2,
                            const float* __restrict__ gW3,
                            _Float16* __restrict__ X0,
                            _Float16* __restrict__ h0, _Float16* __restrict__ h1,
                            _Float16* __restrict__ h2,
                            _Float16* __restrict__ Wc0, _Float16* __restrict__ Wc1,
                            _Float16* __restrict__ Wc2, _Float16* __restrict__ Wc3,
                            _Float16* __restrict__ gW1c, _Float16* __restrict__ gW2c,
                            _Float16* __restrict__ gW3c)
{
    const int N_X  = 4096 * 288;
    const int N_Z  = 4096 * 32;
    const int N_W0 = 8 * 512 * 320;
    const int N_W12 = 8 * 512 * 544;
    const int N_W3 = 8 * 96 * 512;
    const int N_G1 = 128 * 320, N_G2 = 128 * 128, N_G3 = 8 * 128;
    const int TOTAL = N_X + N_Z + 3 * N_Z + N_W0 + 2 * N_W12 + N_W3 + N_G1 + N_G2 + N_G3;

    for (int i = blockIdx.x * blockDim.x + threadIdx.x; i < TOTAL;
         i += gridDim.x * blockDim.x) {
        int j = i;
        if (j < N_X) { int b = j / 288, k = j - b * 288; X0[b * 320 + k] = (_Float16)x[j]; continue; }
        j -= N_X;
        if (j < N_Z) { int b = j / 32, k = j - b * 32; X0[b * 320 + 288 + k] = (_Float16)z[j]; continue; }
        j -= N_Z;
        if (j < 3 * N_Z) {
            int buf = j / N_Z; int r = j - buf * N_Z;
            int b = r / 32, k = r - b * 32;
            _Float16* h = (buf == 0) ? h0 : ((buf == 1) ? h1 : h2);
            h[b * 544 + 512 + k] = (_Float16)z[r];
            continue;
        }
        j -= 3 * N_Z;
        if (j < N_W0)  { Wc0[j] = (_Float16)W0[j]; continue; } j -= N_W0;
        if (j < N_W12) { Wc1[j] = (_Float16)W1[j]; continue; } j -= N_W12;
        if (j < N_W12) { Wc2[j] = (_Float16)W2[j]; continue; } j -= N_W12;
        if (j < N_W3)  { Wc3[j] = (_Float16)W3[j]; continue; } j -= N_W3;
        if (j < N_G1)  { gW1c[j] = (_Float16)gW1[j]; continue; } j -= N_G1;
        if (j < N_G2)  { gW2c[j] = (_Float16)gW2[j]; continue; } j -= N_G2;
        gW3c[j] = (_Float16)gW3[j];
    }
}

// ---------------------------------------------------------------------------
// plain GEMM for the gating layers: out[m][n] = elu(sum_k A[m][k]*W[n][k] + bias[n])
// N = 128 fixed (one N-block). grid = (1, M/128). 256 threads, 4 waves,
// 128x128 tile, 16x16x32 f16 MFMA, BK=32, global_load_lds staging.
// ---------------------------------------------------------------------------
template <bool ELU_ACT>
__launch_bounds__(256)
__global__ void gemm_plain(const _Float16* __restrict__ A, int lda,
                           const _Float16* __restrict__ W, int ldw, int K,
                           const float* __restrict__ bias,
                           _Float16* __restrict__ out, int ldo)
{
    __shared__ _Float16 sA[128 * 32];
    __shared__ _Float16 sB[128 * 32];

    const int tid = threadIdx.x;
    const int l = tid & 63;
    const int w = tid >> 6;
    const int wm = w >> 1, wn = w & 1;
    const int m0 = blockIdx.y * 128;

    // staging addresses (chunk c covers rows c*64..c*64+63; wave w does rows w*16..)
    const int sub = l >> 2;          // 0..15
    const int kc  = (l & 3) * 8;     // 0,8,16,24  (fp16 elements)
    const int row0 = w * 16 + sub;
    const _Float16* gA0 = A + (size_t)(m0 + row0) * lda + kc;
    const _Float16* gA1 = gA0 + (size_t)64 * lda;
    const _Float16* gB0 = W + (size_t)row0 * ldw + kc;
    const _Float16* gB1 = W + (size_t)(row0 + 64) * ldw + kc;
    _Float16* sA0 = sA + w * 512;
    _Float16* sA1 = sA + 2048 + w * 512;
    _Float16* sB0 = sB + w * 512;
    _Float16* sB1 = sB + 2048 + w * 512;

    const int mi = l & 15, quad = l >> 4;
    const _Float16* rA = sA + (wm * 64 + mi) * 32 + quad * 8;
    const _Float16* rB = sB + (wn * 64 + mi) * 32 + quad * 8;

    floatx4 acc[4][4] = {};

    for (int k0 = 0; k0 < K; k0 += 32) {
        __syncthreads();
        async_ld16(gA0 + k0, sA0);
        async_ld16(gA1 + k0, sA1);
        async_ld16(gB0 + k0, sB0);
        async_ld16(gB1 + k0, sB1);
        __syncthreads();
        half8 af[4], bf[4];
#pragma unroll
        for (int i = 0; i < 4; i++) af[i] = *(const half8*)(rA + i * 16 * 32);
#pragma unroll
        for (int j = 0; j < 4; j++) bf[j] = *(const half8*)(rB + j * 16 * 32);
#pragma unroll
        for (int i = 0; i < 4; i++)
#pragma unroll
            for (int j = 0; j < 4; j++)
                acc[i][j] = __builtin_amdgcn_mfma_f32_16x16x32_f16(af[i], bf[j], acc[i][j], 0, 0, 0);
    }

    // epilogue: C/D layout col = lane&15, row = (lane>>4)*4 + reg
#pragma unroll
    for (int i = 0; i < 4; i++)
#pragma unroll
        for (int j = 0; j < 4; j++) {
            int n = wn * 64 + j * 16 + mi;
            float bn = bias[n];
#pragma unroll
            for (int r = 0; r < 4; r++) {
                int m = m0 + wm * 64 + i * 16 + quad * 4 + r;
                float v = acc[i][j][r] + bn;
                if (ELU_ACT) v = elu_f(v);
                out[(size_t)m * ldo + n] = (_Float16)v;
            }
        }
}

// ---------------------------------------------------------------------------
// gating layer 3 + softmax: g[row][e] = softmax_e(gh2[row]·gW3[e] + gb3[e])
// one wave per row; lane l: e = l>>3, 8 lanes each cover 16 of K=128.
// ---------------------------------------------------------------------------
__global__ void gate3_softmax(const _Float16* __restrict__ gh2,
                              const _Float16* __restrict__ gw3,
                              const float* __restrict__ gb3,
                              float* __restrict__ g)
{
    const int l = threadIdx.x & 63;
    const int w = threadIdx.x >> 6;
    const int e = l >> 3, kk = l & 7;
    for (int row = blockIdx.x * 4 + w; row < 4096; row += gridDim.x * 4) {
        const _Float16* hr = gh2 + (size_t)row * 128;
        const _Float16* wr = gw3 + (size_t)e * 128;
        float s = 0.f;
#pragma unroll
        for (int t = 0; t < 16; t++)
            s += (float)hr[kk * 16 + t] * (float)wr[kk * 16 + t];
        s += __shfl_xor(s, 1);
        s += __shfl_xor(s, 2);
        s += __shfl_xor(s, 4);            // all 8 lanes of e-group have full dot
        float logit = s + gb3[e];
        float mx = logit;
        mx = fmaxf(mx, __shfl_xor(mx, 8));
        mx = fmaxf(mx, __shfl_xor(mx, 16));
        mx = fmaxf(mx, __shfl_xor(mx, 32));  // global max over the 8 experts
        float ve = __expf(logit - mx);
        float ssum = ve;
        ssum += __shfl_xor(ssum, 1);
        ssum += __shfl_xor(ssum, 2);
        ssum += __shfl_xor(ssum, 4);
        ssum += __shfl_xor(ssum, 8);
        ssum += __shfl_xor(ssum, 16);
        ssum += __shfl_xor(ssum, 32);     // = 8 * sum_e exp(...)
        float gv = ve / (ssum * 0.125f);
        if (kk == 0) g[(size_t)row * 8 + e] = gv;
    }
}

// ---------------------------------------------------------------------------
// blended expert GEMM:
//   out[m][o] = act( sum_e g[m][e] * ( sum_k A[m][k]*W[e*H+o][k] + bias[e*H+o] ) )
// N-block covers 16 o-cols x 8 experts = 128 cols; c_local = e*16 + j.
// grid = (Hdim/16, M/128). Per-wave partial blend over its 4 experts,
// cross-wave-column reduce through LDS.
// ---------------------------------------------------------------------------
template <bool ELU_ACT, typename OUT_T>
__launch_bounds__(256)
__global__ void gemm_blend(const _Float16* __restrict__ A, int lda,
                           const _Float16* __restrict__ W, int ldw,
                           int Hdim, int K,
                           const float* __restrict__ g,
                           const float* __restrict__ bias,
                           OUT_T* __restrict__ out, int ldo)
{
    __shared__ _Float16 sA[128 * 32];
    __shared__ _Float16 sB[128 * 32];
    __shared__ float sg[128][9];        // +1 pad: quads hit distinct banks
    __shared__ float sbias[8][16];
    __shared__ float sred[2][64][17];   // [wm][m_local][jj], padded

    const int tid = threadIdx.x;
    const int l = tid & 63;
    const int w = tid >> 6;
    const int wm = w >> 1, wn = w & 1;
    const int o0 = blockIdx.x * 16;
    const int m0 = blockIdx.y * 128;

    for (int t = tid; t < 128 * 8; t += 256)
        sg[t >> 3][t & 7] = g[(size_t)(m0 + (t >> 3)) * 8 + (t & 7)];
    for (int t = tid; t < 128; t += 256)
        sbias[t >> 4][t & 15] = bias[(t >> 4) * Hdim + o0 + (t & 15)];

    const int sub = l >> 2;
    const int kc  = (l & 3) * 8;
    const int row0 = w * 16 + sub;
    const _Float16* gA0 = A + (size_t)(m0 + row0) * lda + kc;
    const _Float16* gA1 = gA0 + (size_t)64 * lda;
    const int c0 = row0, c1 = row0 + 64;
    const _Float16* gB0 = W + (size_t)((c0 >> 4) * Hdim + o0 + (c0 & 15)) * ldw + kc;
    const _Float16* gB1 = W + (size_t)((c1 >> 4) * Hdim + o0 + (c1 & 15)) * ldw + kc;
    _Float16* sA0 = sA + w * 512;
    _Float16* sA1 = sA + 2048 + w * 512;
    _Float16* sB0 = sB + w * 512;
    _Float16* sB1 = sB + 2048 + w * 512;

    const int mi = l & 15, quad = l >> 4;
    const _Float16* rA = sA + (wm * 64 + mi) * 32 + quad * 8;
    const _Float16* rB = sB + (wn * 64 + mi) * 32 + quad * 8;

    floatx4 acc[4][4] = {};

    for (int k0 = 0; k0 < K; k0 += 32) {
        __syncthreads();
        async_ld16(gA0 + k0, sA0);
        async_ld16(gA1 + k0, sA1);
        async_ld16(gB0 + k0, sB0);
        async_ld16(gB1 + k0, sB1);
        __syncthreads();
        half8 af[4], bf[4];
#pragma unroll
        for (int i = 0; i < 4; i++) af[i] = *(const half8*)(rA + i * 16 * 32);
#pragma unroll
        for (int j = 0; j < 4; j++) bf[j] = *(const half8*)(rB + j * 16 * 32);
#pragma unroll
        for (int i = 0; i < 4; i++)
#pragma unroll
            for (int j = 0; j < 4; j++)
                acc[i][j] = __builtin_amdgcn_mfma_f32_16x16x32_f16(af[i], bf[j], acc[i][j], 0, 0, 0);
    }

    // blend epilogue. This wave's experts: e = wn*4 + j (j = its 4 column tiles).
    float p[4][4];
#pragma unroll
    for (int i = 0; i < 4; i++)
#pragma unroll
        for (int r = 0; r < 4; r++) {
            int mloc = wm * 64 + i * 16 + quad * 4 + r;
            float s = 0.f;
#pragma unroll
            for (int j = 0; j < 4; j++) {
                int e = wn * 4 + j;
                s += sg[mloc][e] * (acc[i][j][r] + sbias[e][mi]);
            }
            p[i][r] = s;
        }

    if (wn == 0) {
#pragma unroll
        for (int i = 0; i < 4; i++)
#pragma unroll
            for (int r = 0; r < 4; r++)
                sred[wm][i * 16 + quad * 4 + r][mi] = p[i][r];
    }
    __syncthreads();
    if (wn == 1) {
#pragma unroll
        for (int i = 0; i < 4; i++)
#pragma unroll
            for (int r = 0; r < 4; r++) {
                int mrel = i * 16 + quad * 4 + r;
                float v = p[i][r] + sred[wm][mrel][mi];
                if (ELU_ACT) v = elu_f(v);
                out[(size_t)(m0 + wm * 64 + mrel) * ldo + o0 + mi] = (OUT_T)v;
            }
    }
}

// ---------------------------------------------------------------------------
extern "C" void kernel_launch(void* const* d_in, const int* in_sizes, int n_in,
                              void* d_out, int out_size, void* d_ws, size_t ws_size,
                              hipStream_t stream)
{
    (void)in_sizes; (void)n_in; (void)out_size; (void)ws_size;
    const float* x   = (const float*)d_in[0];
    const float* z   = (const float*)d_in[1];
    const float* W0  = (const float*)d_in[2];
    const float* b0  = (const float*)d_in[3];
    const float* W1  = (const float*)d_in[4];
    const float* b1  = (const float*)d_in[5];
    const float* W2  = (const float*)d_in[6];
    const float* b2  = (const float*)d_in[7];
    const float* W3  = (const float*)d_in[8];
    const float* b3  = (const float*)d_in[9];
    const float* gW1 = (const float*)d_in[10];
    const float* gb1 = (const float*)d_in[11];
    const float* gW2 = (const float*)d_in[12];
    const float* gb2 = (const float*)d_in[13];
    const float* gW3 = (const float*)d_in[14];
    const float* gb3 = (const float*)d_in[15];

    char* p = (char*)d_ws;
    auto alloc = [&](size_t n) { char* r = p; p += (n + 255) & ~(size_t)255; return r; };
    _Float16* X0   = (_Float16*)alloc((size_t)4096 * 320 * 2);
    _Float16* h0   = (_Float16*)alloc((size_t)4096 * 544 * 2);
    _Float16* h1   = (_Float16*)alloc((size_t)4096 * 544 * 2);
    _Float16* h2   = (_Float16*)alloc((size_t)4096 * 544 * 2);
    _Float16* Wc0  = (_Float16*)alloc((size_t)8 * 512 * 320 * 2);
    _Float16* Wc1  = (_Float16*)alloc((size_t)8 * 512 * 544 * 2);
    _Float16* Wc2  = (_Float16*)alloc((size_t)8 * 512 * 544 * 2);
    _Float16* Wc3  = (_Float16*)alloc((size_t)8 * 96 * 512 * 2);
    _Float16* gW1c = (_Float16*)alloc((size_t)128 * 320 * 2);
    _Float16* gW2c = (_Float16*)alloc((size_t)128 * 128 * 2);
    _Float16* gW3c = (_Float16*)alloc((size_t)8 * 128 * 2);
    _Float16* gh1  = (_Float16*)alloc((size_t)4096 * 128 * 2);
    _Float16* gh2  = (_Float16*)alloc((size_t)4096 * 128 * 2);
    float*    g    = (float*)alloc((size_t)4096 * 8 * 4);

    prep_kernel<<<4096, 256, 0, stream>>>(x, z, W0, W1, W2, W3, gW1, gW2, gW3,
                                          X0, h0, h1, h2, Wc0, Wc1, Wc2, Wc3,
                                          gW1c, gW2c, gW3c);

    gemm_plain<true><<<dim3(1, 32), 256, 0, stream>>>(X0, 320, gW1c, 320, 320, gb1, gh1, 128);
    gemm_plain<true><<<dim3(1, 32), 256, 0, stream>>>(gh1, 128, gW2c, 128, 128, gb2, gh2, 128);
    gate3_softmax<<<256, 256, 0, stream>>>(gh2, gW3c, gb3, g);

    gemm_blend<true, _Float16><<<dim3(32, 32), 256, 0, stream>>>(X0, 320, Wc0, 320, 512, 320, g, b0, h0, 544);
    gemm_blend<true, _Float16><<<dim3(32, 32), 256, 0, stream>>>(h0, 544, Wc1, 544, 512, 544, g, b1, h1, 544);
    gemm_blend<true, _Float16><<<dim3(32, 32), 256, 0, stream>>>(h1, 544, Wc2, 544, 512, 544, g, b2, h2, 544);
    gemm_blend<false, float><<<dim3(6, 32), 256, 0, stream>>>(h2, 544, Wc3, 512, 96, 512, g, b3, (float*)d_out, 96);
}

// Round 2
// 234.371 us; speedup vs baseline: 1.0764x; 1.0764x over previous
//
#include <hip/hip_runtime.h>
#include <hip/hip_fp16.h>

typedef _Float16 half8 __attribute__((ext_vector_type(8)));
typedef _Float16 half4 __attribute__((ext_vector_type(4)));
typedef float floatx4 __attribute__((ext_vector_type(4)));

__device__ __forceinline__ void async_ld16(const void* g, void* l) {
    __builtin_amdgcn_global_load_lds(
        (const __attribute__((address_space(1))) char*)g,
        (__attribute__((address_space(3))) char*)l, 16, 0, 0);
}

__device__ __forceinline__ float elu_f(float v) {
    return v > 0.f ? v : expm1f(v);
}

// ---------------------------------------------------------------------------
// prep: fp32 -> fp16 working buffers, vectorized 4 elements/thread.
//  X0  [4096][320] = [x | z]
//  h0/h1/h2 [4096][544]: cols 512..543 = z
// All section sizes and row strides are multiples of 4, so a float4 chunk
// never crosses a row boundary.
// ---------------------------------------------------------------------------
__global__ void prep_kernel(const float* __restrict__ x, const float* __restrict__ z,
                            const float* __restrict__ W0, const float* __restrict__ W1,
                            const float* __restrict__ W2, const float* __restrict__ W3,
                            const float* __restrict__ gW1, const float* __restrict__ gW2,
                            const float* __restrict__ gW3,
                            _Float16* __restrict__ X0,
                            _Float16* __restrict__ h0, _Float16* __restrict__ h1,
                            _Float16* __restrict__ h2,
                            _Float16* __restrict__ Wc0, _Float16* __restrict__ Wc1,
                            _Float16* __restrict__ Wc2, _Float16* __restrict__ Wc3,
                            _Float16* __restrict__ gW1c, _Float16* __restrict__ gW2c,
                            _Float16* __restrict__ gW3c)
{
    const int N_X4  = 4096 * 288 / 4;
    const int N_Z4  = 4096 * 32 / 4;
    const int N_W04 = 8 * 512 * 320 / 4;
    const int N_W124 = 8 * 512 * 544 / 4;
    const int N_W34 = 8 * 96 * 512 / 4;
    const int N_G14 = 128 * 320 / 4, N_G24 = 128 * 128 / 4, N_G34 = 8 * 128 / 4;
    const int TOTAL4 = N_X4 + N_Z4 + 3 * N_Z4 + N_W04 + 2 * N_W124 + N_W34
                     + N_G14 + N_G24 + N_G34;

    auto cvt = [](const float* src, int j4) -> half4 {
        float4 f = ((const float4*)src)[j4];
        half4 h; h.x = (_Float16)f.x; h.y = (_Float16)f.y;
        h.z = (_Float16)f.z; h.w = (_Float16)f.w; return h;
    };

    for (int i = blockIdx.x * blockDim.x + threadIdx.x; i < TOTAL4;
         i += gridDim.x * blockDim.x) {
        int j = i;
        if (j < N_X4) {
            int b = j / 72, k4 = j - b * 72;          // 288/4 = 72
            *(half4*)(X0 + b * 320 + k4 * 4) = cvt(x, j);
            continue;
        }
        j -= N_X4;
        if (j < N_Z4) {
            int b = j / 8, k4 = j - b * 8;            // 32/4 = 8
            *(half4*)(X0 + b * 320 + 288 + k4 * 4) = cvt(z, j);
            continue;
        }
        j -= N_Z4;
        if (j < 3 * N_Z4) {
            int buf = j / N_Z4; int r = j - buf * N_Z4;
            int b = r / 8, k4 = r - b * 8;
            _Float16* h = (buf == 0) ? h0 : ((buf == 1) ? h1 : h2);
            *(half4*)(h + b * 544 + 512 + k4 * 4) = cvt(z, r);
            continue;
        }
        j -= 3 * N_Z4;
        if (j < N_W04)  { *(half4*)(Wc0 + j * 4) = cvt(W0, j); continue; } j -= N_W04;
        if (j < N_W124) { *(half4*)(Wc1 + j * 4) = cvt(W1, j); continue; } j -= N_W124;
        if (j < N_W124) { *(half4*)(Wc2 + j * 4) = cvt(W2, j); continue; } j -= N_W124;
        if (j < N_W34)  { *(half4*)(Wc3 + j * 4) = cvt(W3, j); continue; } j -= N_W34;
        if (j < N_G14)  { *(half4*)(gW1c + j * 4) = cvt(gW1, j); continue; } j -= N_G14;
        if (j < N_G24)  { *(half4*)(gW2c + j * 4) = cvt(gW2, j); continue; } j -= N_G24;
        *(half4*)(gW3c + j * 4) = cvt(gW3, j);
    }
}

// ---------------------------------------------------------------------------
// fused gating: per block of 128 rows, computes
//   gh1 = elu(X0 @ gW1^T + gb1)       (K=320, MFMA, tile kept in LDS)
//   gh2 = elu(gh1 @ gW2^T + gb2)      (K=128, A from LDS, B staged per-32)
//   g   = softmax(gh2 @ gW3^T + gb3)  (wave-level)
// grid = 32 blocks x 256 threads. One global write: g [4096][8] fp32.
// ---------------------------------------------------------------------------
__launch_bounds__(256)
__global__ void gating_fused(const _Float16* __restrict__ X0,
                             const _Float16* __restrict__ gW1c,
                             const _Float16* __restrict__ gW2c,
                             const _Float16* __restrict__ gW3c,
                             const float* __restrict__ gb1,
                             const float* __restrict__ gb2,
                             const float* __restrict__ gb3,
                             float* __restrict__ g)
{
    __shared__ _Float16 sA[128 * 32];
    __shared__ _Float16 sB[128 * 32];
    __shared__ _Float16 h1t[128 * 136];   // padded stride 136 (bank spread)
    __shared__ _Float16 sW3[8 * 128];

    const int tid = threadIdx.x;
    const int l = tid & 63;
    const int w = tid >> 6;
    const int wm = w >> 1, wn = w & 1;
    const int m0 = blockIdx.x * 128;

    for (int t = tid; t < 8 * 128; t += 256) sW3[t] = gW3c[t];

    const int sub = l >> 2;
    const int kc  = (l & 3) * 8;
    const int row0 = w * 16 + sub;
    const _Float16* gA0 = X0 + (size_t)(m0 + row0) * 320 + kc;
    const _Float16* gA1 = gA0 + (size_t)64 * 320;
    const _Float16* gB0 = gW1c + (size_t)row0 * 320 + kc;
    const _Float16* gB1 = gW1c + (size_t)(row0 + 64) * 320 + kc;
    _Float16* sA0 = sA + w * 512;
    _Float16* sA1 = sA + 2048 + w * 512;
    _Float16* sB0 = sB + w * 512;
    _Float16* sB1 = sB + 2048 + w * 512;

    const int mi = l & 15, quad = l >> 4;
    const _Float16* rA = sA + (wm * 64 + mi) * 32 + quad * 8;
    const _Float16* rB = sB + (wn * 64 + mi) * 32 + quad * 8;

    floatx4 acc[4][4] = {};

    // ---- GEMM1: K=320 ----
    for (int k0 = 0; k0 < 320; k0 += 32) {
        __syncthreads();
        async_ld16(gA0 + k0, sA0);
        async_ld16(gA1 + k0, sA1);
        async_ld16(gB0 + k0, sB0);
        async_ld16(gB1 + k0, sB1);
        __syncthreads();
        half8 af[4], bf[4];
#pragma unroll
        for (int i = 0; i < 4; i++) af[i] = *(const half8*)(rA + i * 16 * 32);
#pragma unroll
        for (int j = 0; j < 4; j++) bf[j] = *(const half8*)(rB + j * 16 * 32);
#pragma unroll
        for (int i = 0; i < 4; i++)
#pragma unroll
            for (int j = 0; j < 4; j++)
                acc[i][j] = __builtin_amdgcn_mfma_f32_16x16x32_f16(af[i], bf[j], acc[i][j], 0, 0, 0);
    }
    __syncthreads();
#pragma unroll
    for (int i = 0; i < 4; i++)
#pragma unroll
        for (int j = 0; j < 4; j++) {
            int n = wn * 64 + j * 16 + mi;
            float bn = gb1[n];
#pragma unroll
            for (int r = 0; r < 4; r++) {
                int mrel = wm * 64 + i * 16 + quad * 4 + r;
                h1t[mrel * 136 + n] = (_Float16)elu_f(acc[i][j][r] + bn);
            }
        }

    // ---- GEMM2: K=128, A = h1t (LDS), B = gW2c staged 32-wide ----
    floatx4 acc2[4][4] = {};
    const _Float16* gB20 = gW2c + (size_t)row0 * 128 + kc;
    const _Float16* gB21 = gW2c + (size_t)(row0 + 64) * 128 + kc;
    const _Float16* rA2b = h1t + (wm * 64 + mi) * 136 + quad * 8;
    for (int ks = 0; ks < 4; ks++) {
        __syncthreads();
        async_ld16(gB20 + ks * 32, sB0);
        async_ld16(gB21 + ks * 32, sB1);
        __syncthreads();
        half8 af[4], bf[4];
#pragma unroll
        for (int i = 0; i < 4; i++) af[i] = *(const half8*)(rA2b + i * 16 * 136 + ks * 32);
#pragma unroll
        for (int j = 0; j < 4; j++) bf[j] = *(const half8*)(rB + j * 16 * 32);
#pragma unroll
        for (int i = 0; i < 4; i++)
#pragma unroll
            for (int j = 0; j < 4; j++)
                acc2[i][j] = __builtin_amdgcn_mfma_f32_16x16x32_f16(af[i], bf[j], acc2[i][j], 0, 0, 0);
    }
    __syncthreads();
#pragma unroll
    for (int i = 0; i < 4; i++)
#pragma unroll
        for (int j = 0; j < 4; j++) {
            int n = wn * 64 + j * 16 + mi;
            float bn = gb2[n];
#pragma unroll
            for (int r = 0; r < 4; r++) {
                int mrel = wm * 64 + i * 16 + quad * 4 + r;
                h1t[mrel * 136 + n] = (_Float16)elu_f(acc2[i][j][r] + bn);
            }
        }
    __syncthreads();

    // ---- gate3 + softmax: wave w handles rows w*32 .. w*32+31 ----
    const int e = l >> 3, kk = l & 7;
    for (int rr = 0; rr < 32; rr++) {
        int row = w * 32 + rr;
        const _Float16* hr = h1t + row * 136 + kk * 16;
        const _Float16* wr = sW3 + e * 128 + kk * 16;
        half8 hv0 = *(const half8*)hr;
        half8 hv1 = *(const half8*)(hr + 8);
        half8 wv0 = *(const half8*)wr;
        half8 wv1 = *(const half8*)(wr + 8);
        float s = 0.f;
#pragma unroll
        for (int t = 0; t < 8; t++)
            s += (float)hv0[t] * (float)wv0[t] + (float)hv1[t] * (float)wv1[t];
        s += __shfl_xor(s, 1);
        s += __shfl_xor(s, 2);
        s += __shfl_xor(s, 4);
        float logit = s + gb3[e];
        float mx = logit;
        mx = fmaxf(mx, __shfl_xor(mx, 8));
        mx = fmaxf(mx, __shfl_xor(mx, 16));
        mx = fmaxf(mx, __shfl_xor(mx, 32));
        float ve = __expf(logit - mx);
        float ssum = ve;
        ssum += __shfl_xor(ssum, 1);
        ssum += __shfl_xor(ssum, 2);
        ssum += __shfl_xor(ssum, 4);
        ssum += __shfl_xor(ssum, 8);
        ssum += __shfl_xor(ssum, 16);
        ssum += __shfl_xor(ssum, 32);
        float gv = ve / (ssum * 0.125f);
        if (kk == 0) g[(size_t)(m0 + row) * 8 + e] = gv;
    }
}

// ---------------------------------------------------------------------------
// blended expert GEMM:
//   out[m][o] = act( sum_e g[m][e] * ( sum_k A[m][k]*W[e*H+o][k] + bias[e*H+o] ) )
// N-block = 16 o-cols x 8 experts = 128 cols; c_local = e*16 + j.
// grid = (Hdim/16, M/128). __launch_bounds__(256,4) pins 4 blocks/CU so the
// 1024-block grid is co-resident in ONE dispatch round. sred overlays the
// dead sA/sB staging space (LDS 30 KB -> 21.5 KB).
// ---------------------------------------------------------------------------
template <bool ELU_ACT, typename OUT_T>
__launch_bounds__(256, 4)
__global__ void gemm_blend(const _Float16* __restrict__ A, int lda,
                           const _Float16* __restrict__ W, int ldw,
                           int Hdim, int K,
                           const float* __restrict__ g,
                           const float* __restrict__ bias,
                           OUT_T* __restrict__ out, int ldo)
{
    __shared__ __align__(16) char smem_raw[16384];
    _Float16* sA = (_Float16*)smem_raw;
    _Float16* sB = (_Float16*)(smem_raw + 8192);
    float* sredf = (float*)smem_raw;      // [2][64][17], used after K-loop
    __shared__ float sg[128][9];
    __shared__ float sbias[8][16];

    const int tid = threadIdx.x;
    const int l = tid & 63;
    const int w = tid >> 6;
    const int wm = w >> 1, wn = w & 1;
    const int o0 = blockIdx.x * 16;
    const int m0 = blockIdx.y * 128;

    for (int t = tid; t < 128 * 8; t += 256)
        sg[t >> 3][t & 7] = g[(size_t)(m0 + (t >> 3)) * 8 + (t & 7)];
    for (int t = tid; t < 128; t += 256)
        sbias[t >> 4][t & 15] = bias[(t >> 4) * Hdim + o0 + (t & 15)];

    const int sub = l >> 2;
    const int kc  = (l & 3) * 8;
    const int row0 = w * 16 + sub;
    const _Float16* gA0 = A + (size_t)(m0 + row0) * lda + kc;
    const _Float16* gA1 = gA0 + (size_t)64 * lda;
    const int c0 = row0, c1 = row0 + 64;
    const _Float16* gB0 = W + (size_t)((c0 >> 4) * Hdim + o0 + (c0 & 15)) * ldw + kc;
    const _Float16* gB1 = W + (size_t)((c1 >> 4) * Hdim + o0 + (c1 & 15)) * ldw + kc;
    _Float16* sA0 = sA + w * 512;
    _Float16* sA1 = sA + 2048 + w * 512;
    _Float16* sB0 = sB + w * 512;
    _Float16* sB1 = sB + 2048 + w * 512;

    const int mi = l & 15, quad = l >> 4;
    const _Float16* rA = sA + (wm * 64 + mi) * 32 + quad * 8;
    const _Float16* rB = sB + (wn * 64 + mi) * 32 + quad * 8;

    floatx4 acc[4][4] = {};

    for (int k0 = 0; k0 < K; k0 += 32) {
        __syncthreads();
        async_ld16(gA0 + k0, sA0);
        async_ld16(gA1 + k0, sA1);
        async_ld16(gB0 + k0, sB0);
        async_ld16(gB1 + k0, sB1);
        __syncthreads();
        half8 af[4], bf[4];
#pragma unroll
        for (int i = 0; i < 4; i++) af[i] = *(const half8*)(rA + i * 16 * 32);
#pragma unroll
        for (int j = 0; j < 4; j++) bf[j] = *(const half8*)(rB + j * 16 * 32);
#pragma unroll
        for (int i = 0; i < 4; i++)
#pragma unroll
            for (int j = 0; j < 4; j++)
                acc[i][j] = __builtin_amdgcn_mfma_f32_16x16x32_f16(af[i], bf[j], acc[i][j], 0, 0, 0);
    }

    // blend epilogue. This wave's experts: e = wn*4 + j.
    float p[4][4];
#pragma unroll
    for (int i = 0; i < 4; i++)
#pragma unroll
        for (int r = 0; r < 4; r++) {
            int mloc = wm * 64 + i * 16 + quad * 4 + r;
            float s = 0.f;
#pragma unroll
            for (int j = 0; j < 4; j++) {
                int e = wn * 4 + j;
                s += sg[mloc][e] * (acc[i][j][r] + sbias[e][mi]);
            }
            p[i][r] = s;
        }

    __syncthreads();   // sA/sB dead for ALL waves; safe to overlay sred
    if (wn == 0) {
#pragma unroll
        for (int i = 0; i < 4; i++)
#pragma unroll
            for (int r = 0; r < 4; r++)
                sredf[(wm * 64 + i * 16 + quad * 4 + r) * 17 + mi] = p[i][r];
    }
    __syncthreads();
    if (wn == 1) {
#pragma unroll
        for (int i = 0; i < 4; i++)
#pragma unroll
            for (int r = 0; r < 4; r++) {
                int mrel = i * 16 + quad * 4 + r;
                float v = p[i][r] + sredf[(wm * 64 + mrel) * 17 + mi];
                if (ELU_ACT) v = elu_f(v);
                out[(size_t)(m0 + wm * 64 + mrel) * ldo + o0 + mi] = (OUT_T)v;
            }
    }
}

// ---------------------------------------------------------------------------
extern "C" void kernel_launch(void* const* d_in, const int* in_sizes, int n_in,
                              void* d_out, int out_size, void* d_ws, size_t ws_size,
                              hipStream_t stream)
{
    (void)in_sizes; (void)n_in; (void)out_size; (void)ws_size;
    const float* x   = (const float*)d_in[0];
    const float* z   = (const float*)d_in[1];
    const float* W0  = (const float*)d_in[2];
    const float* b0  = (const float*)d_in[3];
    const float* W1  = (const float*)d_in[4];
    const float* b1  = (const float*)d_in[5];
    const float* W2  = (const float*)d_in[6];
    const float* b2  = (const float*)d_in[7];
    const float* W3  = (const float*)d_in[8];
    const float* b3  = (const float*)d_in[9];
    const float* gW1 = (const float*)d_in[10];
    const float* gb1 = (const float*)d_in[11];
    const float* gW2 = (const float*)d_in[12];
    const float* gb2 = (const float*)d_in[13];
    const float* gW3 = (const float*)d_in[14];
    const float* gb3 = (const float*)d_in[15];

    char* p = (char*)d_ws;
    auto alloc = [&](size_t n) { char* r = p; p += (n + 255) & ~(size_t)255; return r; };
    _Float16* X0   = (_Float16*)alloc((size_t)4096 * 320 * 2);
    _Float16* h0   = (_Float16*)alloc((size_t)4096 * 544 * 2);
    _Float16* h1   = (_Float16*)alloc((size_t)4096 * 544 * 2);
    _Float16* h2   = (_Float16*)alloc((size_t)4096 * 544 * 2);
    _Float16* Wc0  = (_Float16*)alloc((size_t)8 * 512 * 320 * 2);
    _Float16* Wc1  = (_Float16*)alloc((size_t)8 * 512 * 544 * 2);
    _Float16* Wc2  = (_Float16*)alloc((size_t)8 * 512 * 544 * 2);
    _Float16* Wc3  = (_Float16*)alloc((size_t)8 * 96 * 512 * 2);
    _Float16* gW1c = (_Float16*)alloc((size_t)128 * 320 * 2);
    _Float16* gW2c = (_Float16*)alloc((size_t)128 * 128 * 2);
    _Float16* gW3c = (_Float16*)alloc((size_t)8 * 128 * 2);
    float*    g    = (float*)alloc((size_t)4096 * 8 * 4);

    prep_kernel<<<2048, 256, 0, stream>>>(x, z, W0, W1, W2, W3, gW1, gW2, gW3,
                                          X0, h0, h1, h2, Wc0, Wc1, Wc2, Wc3,
                                          gW1c, gW2c, gW3c);

    gating_fused<<<32, 256, 0, stream>>>(X0, gW1c, gW2c, gW3c, gb1, gb2, gb3, g);

    gemm_blend<true, _Float16><<<dim3(32, 32), 256, 0, stream>>>(X0, 320, Wc0, 320, 512, 320, g, b0, h0, 544);
    gemm_blend<true, _Float16><<<dim3(32, 32), 256, 0, stream>>>(h0, 544, Wc1, 544, 512, 544, g, b1, h1, 544);
    gemm_blend<true, _Float16><<<dim3(32, 32), 256, 0, stream>>>(h1, 544, Wc2, 544, 512, 544, g, b2, h2, 544);
    gemm_blend<false, float><<<dim3(6, 32), 256, 0, stream>>>(h2, 544, Wc3, 512, 96, 512, g, b3, (float*)d_out, 96);
}